// Round 13
// baseline (223.023 us; speedup 1.0000x reference)
//
#include <hip/hip_runtime.h>

// B=4,S=2048,E=512,H=8. Linear attention (no softmax) collapsed to GEMM chain:
//  out[b] = q~[b]*C~[b]+bo,  C~[b]=(1/512) sum_h U~[h] G~[b] Z~[h]^T
// Multi-launch, balanced units, no atomics, flat 122MB workspace (ws is 268MB).
// GEMMs: NT 64x128 tiles, BK=128, 48KB single-buffered LDS,
// global_load_lds(16B) pre-swizzled source + XOR-swizzled ds_read_b128,
// 16x16x32 bf16 MFMA, f32 acc. Transposes fully vectorized (f32x4 in, u16x4 out).

typedef long long i64;
typedef unsigned short u16;
typedef __attribute__((ext_vector_type(8))) short bf16x8;
typedef __attribute__((ext_vector_type(4))) float f32x4;

#define EB 512
#define EP 640
#define SQ 2048
#define NB 4
#define NH 8
#define HEP 5120

// ---- flat workspace byte offsets (total 122,036,224 < ws 268MB) ----
#define OFF_KT    0ll           // 10,485,760  bf16 kT [4][640][2048]
#define OFF_VT    10485760ll    // 10,485,760  bf16 vT
#define OFF_WQT   20971520ll    //  5,242,880  bf16 WqT [8][640][512]
#define OFF_WKT   26214400ll    //  5,242,880
#define OFF_WVT   31457280ll    //  5,242,880
#define OFF_WOB   36700160ll    //  4,194,304  bf16 Wo [512][4096]
#define OFF_ZCAT  40894464ll    //  5,242,880  bf16 Zcat [512][5120]
#define OFF_UCAT  46137344ll    //  6,553,600  bf16 Ucat [640][5120]
#define OFF_GP    52690944ll    // 13,107,200  f32 G partials [4][2][50][8192]
#define OFF_GB    65798144ll    //  3,276,800  bf16 Gb [4][640][640]
#define OFF_ZGC   69074944ll    // 20,971,520  bf16 ZGcat [4][512][5120]
#define OFF_CTP   90046464ll    // 20,971,520  f32 CT partials [4][4][40][8192]
#define OFF_QB    111017984ll   //  8,388,608  bf16 q [4][2048][512]
#define OFF_CTB   119406592ll   //  2,621,440  bf16 CTb [4][512][640]
#define OFF_RB    122028032ll   //      8,192  f32 rb [4][512]

__device__ __forceinline__ u16 f2bf(float x) {
    unsigned u = __float_as_uint(x);
    return (u16)((u + 0x7fffu + ((u >> 16) & 1u)) >> 16);
}

__device__ __forceinline__ void gload16(const void* g, void* l) {
    __builtin_amdgcn_global_load_lds(
        (const __attribute__((address_space(1))) unsigned int*)g,
        (__attribute__((address_space(3))) unsigned int*)l, 16, 0, 0);
}

// ====== GEMM body: C = A*B^T, 64x128 tile, BK=128, single-buffered 48KB LDS ======
// LDS: A half0 [0,8K), A half1 [8K,16K), B half0 [16K,32K), B half1 [32K,48K).
// 4 waves: wave w owns cols w*32..w*32+31 (fn 0..1), all 64 rows (fm 0..3).
__device__ __forceinline__ void gemm64(
    const u16* __restrict__ A, i64 lda, const u16* __restrict__ B, i64 ldb,
    int bx, int by, int K, int epi, void* Cv, i64 ldc,
    const float* rbias, const float* bo, char* pool)
{
    const i64 m0 = (i64)bx * 64, n0 = (i64)by * 128;
    const int tid = threadIdx.x, lane = tid & 63, wid = tid >> 6;
    const int g = lane >> 4, li = lane & 15;

    const u16* gsrc[12]; char* ldst[12];
#pragma unroll
    for (int i = 0; i < 12; ++i) {
        const int c = wid * 12 + i;
        const bool isA = c < 16;
        const int half = isA ? (c >> 3) : ((c - 16) >> 4);
        const int cc = isA ? (c & 7) : ((c - 16) & 15);
        const int rr = cc * 8 + (lane >> 3);
        const int gc = (half << 6) + (((lane & 7) ^ (rr & 7)) << 3);
        gsrc[i] = (isA ? A + (m0 + rr) * lda : B + (n0 + rr) * ldb) + gc;
        ldst[i] = pool + (isA ? half * 8192 : 16384 + half * 16384)
                       + cc * 1024 + lane * 16;
    }

    f32x4 acc[4][2];
#pragma unroll
    for (int a_ = 0; a_ < 4; ++a_)
#pragma unroll
        for (int b_ = 0; b_ < 2; ++b_) acc[a_][b_] = (f32x4){0.f, 0.f, 0.f, 0.f};

    const int nIt = K >> 7;
    for (int it = 0; it < nIt; ++it) {
        const i64 k0 = (i64)it << 7;
#pragma unroll
        for (int i = 0; i < 12; ++i) gload16(gsrc[i] + k0, ldst[i]);
        __syncthreads();
#pragma unroll
        for (int ks = 0; ks < 4; ++ks) {
            const int h = ks >> 1, s2 = ks & 1;
            bf16x8 af[4], bf[2];
#pragma unroll
            for (int fm = 0; fm < 4; ++fm) {
                const int row = fm * 16 + li;
                const int slot = (s2 * 4 + g) ^ (row & 7);
                af[fm] = *(const bf16x8*)(pool + h * 8192 + row * 128 + slot * 16);
            }
#pragma unroll
            for (int fn = 0; fn < 2; ++fn) {
                const int row = wid * 32 + fn * 16 + li;
                const int slot = (s2 * 4 + g) ^ (row & 7);
                bf[fn] = *(const bf16x8*)(pool + 16384 + h * 16384 + row * 128 + slot * 16);
            }
#pragma unroll
            for (int fm = 0; fm < 4; ++fm)
#pragma unroll
                for (int fn = 0; fn < 2; ++fn)
                    acc[fm][fn] = __builtin_amdgcn_mfma_f32_16x16x32_bf16(
                        af[fm], bf[fn], acc[fm][fn], 0, 0, 0);
        }
        __syncthreads();
    }

    if (epi == 0) {
        u16* C = (u16*)Cv;
#pragma unroll
        for (int fm = 0; fm < 4; ++fm)
#pragma unroll
            for (int fn = 0; fn < 2; ++fn) {
                const i64 col = n0 + wid * 32 + fn * 16 + li;
#pragma unroll
                for (int q = 0; q < 4; ++q) {
                    const i64 row = m0 + fm * 16 + g * 4 + q;
                    C[row * ldc + col] = f2bf(acc[fm][fn][q]);
                }
            }
    } else if (epi == 2) {
        float* C = (float*)Cv;
#pragma unroll
        for (int fn = 0; fn < 2; ++fn) {
            const i64 col = n0 + wid * 32 + fn * 16 + li;
            const float bb = rbias[col] + bo[col];
#pragma unroll
            for (int fm = 0; fm < 4; ++fm)
#pragma unroll
                for (int q = 0; q < 4; ++q) {
                    const i64 row = m0 + fm * 16 + g * 4 + q;
                    C[row * ldc + col] = acc[fm][fn][q] + bb;
                }
        }
    } else {   // epi 3: fragment-layout partial, fully coalesced f32x4
        float* C = (float*)Cv;
#pragma unroll
        for (int fm = 0; fm < 4; ++fm)
#pragma unroll
            for (int fn = 0; fn < 2; ++fn)
                *(f32x4*)(C + (fm * 2 + fn) * 1024 + tid * 4) = acc[fm][fn];
    }
}

#define GEMM_LDS __shared__ __align__(16) char pool[49152];

// ===== vectorized transpose+aug: f32 [Sx512] -> bf16 [640xS], 64x64 tile =====
// load: float4 global reads -> LDS [64][65]; store: pack 4 -> ushort4 writes.
__device__ __forceinline__ void transpose_dev(
    const float* __restrict__ src, const float* __restrict__ aug,
    u16* __restrict__ dst, int S, int bx, int by, char* pool)
{
    const int s0 = bx * 64, e0 = by * 64;
    const int t = threadIdx.x;
    if (e0 >= EB) {
#pragma unroll
        for (int i = 0; i < 4; ++i) {
            const int idx = i * 256 + t;
            const int er = idx >> 4, c4 = (idx & 15) << 2;
            const int e = e0 + er;
            ushort4 o = {0, 0, 0, 0};
            if (e == EB) {
                o.x = f2bf(aug ? aug[s0 + c4 + 0] : 1.0f);
                o.y = f2bf(aug ? aug[s0 + c4 + 1] : 1.0f);
                o.z = f2bf(aug ? aug[s0 + c4 + 2] : 1.0f);
                o.w = f2bf(aug ? aug[s0 + c4 + 3] : 1.0f);
            }
            *(ushort4*)&dst[(i64)e * S + s0 + c4] = o;
        }
        return;
    }
    float (*tile)[65] = (float(*)[65])pool;   // 16,640 B
#pragma unroll
    for (int i = 0; i < 4; ++i) {
        const int idx = i * 256 + t;
        const int sr = idx >> 4, e4 = (idx & 15) << 2;
        const float4 v = *(const float4*)&src[(i64)(s0 + sr) * EB + e0 + e4];
        tile[sr][e4 + 0] = v.x;
        tile[sr][e4 + 1] = v.y;
        tile[sr][e4 + 2] = v.z;
        tile[sr][e4 + 3] = v.w;
    }
    __syncthreads();
#pragma unroll
    for (int i = 0; i < 4; ++i) {
        const int idx = i * 256 + t;
        const int er = idx >> 4, c4 = (idx & 15) << 2;
        ushort4 o;
        o.x = f2bf(tile[c4 + 0][er]);
        o.y = f2bf(tile[c4 + 1][er]);
        o.z = f2bf(tile[c4 + 2][er]);
        o.w = f2bf(tile[c4 + 3][er]);
        *(ushort4*)&dst[(i64)(e0 + er) * S + s0 + c4] = o;
    }
}

__device__ __forceinline__ void cvt_dev(const float4* in, ushort4* outp,
                                        float alpha, i64 i)
{
    const float4 v = in[i];
    ushort4 o;
    o.x = f2bf(v.x * alpha); o.y = f2bf(v.y * alpha);
    o.z = f2bf(v.z * alpha); o.w = f2bf(v.w * alpha);
    outp[i] = o;
}

// ===== L0 prep: transposes + Wo convert + q convert (6016 blocks)
__global__ __launch_bounds__(256)
void prep(const float* __restrict__ q, const float* __restrict__ k,
          const float* __restrict__ v,
          const float* __restrict__ Wq, const float* __restrict__ bq,
          const float* __restrict__ Wk, const float* __restrict__ bk,
          const float* __restrict__ Wv, const float* __restrict__ bv,
          const float* __restrict__ Wo, char* __restrict__ ws)
{
    __shared__ __align__(16) char pool[16640];
    const int u = blockIdx.x, t = threadIdx.x;
    if (u < 1280) {               // kT
        const int bz = u / 320, r = u % 320;
        transpose_dev(k + (i64)bz * SQ * EB, nullptr,
                      (u16*)(ws + OFF_KT) + (i64)bz * EP * SQ, SQ,
                      r % 32, r / 32, pool);
    } else if (u < 2560) {        // vT
        const int l = u - 1280, bz = l / 320, r = l % 320;
        transpose_dev(v + (i64)bz * SQ * EB, nullptr,
                      (u16*)(ws + OFF_VT) + (i64)bz * EP * SQ, SQ,
                      r % 32, r / 32, pool);
    } else if (u < 3200) {        // WqT
        const int l = u - 2560, bz = l / 80, r = l % 80;
        transpose_dev(Wq + (i64)bz * EB * EB, bq + (i64)bz * EB,
                      (u16*)(ws + OFF_WQT) + (i64)bz * EP * EB, EB,
                      r % 8, r / 8, pool);
    } else if (u < 3840) {        // WkT
        const int l = u - 3200, bz = l / 80, r = l % 80;
        transpose_dev(Wk + (i64)bz * EB * EB, bk + (i64)bz * EB,
                      (u16*)(ws + OFF_WKT) + (i64)bz * EP * EB, EB,
                      r % 8, r / 8, pool);
    } else if (u < 4480) {        // WvT
        const int l = u - 3840, bz = l / 80, r = l % 80;
        transpose_dev(Wv + (i64)bz * EB * EB, bv + (i64)bz * EB,
                      (u16*)(ws + OFF_WVT) + (i64)bz * EP * EB, EB,
                      r % 8, r / 8, pool);
    } else if (u < 4992) {        // Wo cvt (512 units x 1024 float4)
        const i64 j = u - 4480;
#pragma unroll
        for (int s = 0; s < 4; ++s)
            cvt_dev((const float4*)Wo, (ushort4*)(ws + OFF_WOB), 1.0f,
                    j * 1024 + s * 256 + t);
    } else {                      // q cvt (1024 units x 1024 float4)
        const i64 j = u - 4992;
#pragma unroll
        for (int s = 0; s < 4; ++s)
            cvt_dev((const float4*)q, (ushort4*)(ws + OFF_QB), 1.0f,
                    j * 1024 + s * 256 + t);
    }
}

// ===== L1 stage1: G splitK2 (400 units, 8it, dispatched FIRST) + U(400)/Z(320), 4it
__global__ __launch_bounds__(256)
void stage1(char* __restrict__ ws)
{
    GEMM_LDS
    const int x = blockIdx.x & 7, o = blockIdx.x >> 3;
    if (o < 50) {                 // G split-K partial (K=1024, epi3)
        const int gu = x * 50 + o;               // 0..399
        const int b = gu / 100, sp = (gu / 50) & 1, r = gu % 50;
        const u16* A = (const u16*)(ws + OFF_KT) + (i64)b * EP * SQ + sp * 1024;
        const u16* B = (const u16*)(ws + OFF_VT) + (i64)b * EP * SQ + sp * 1024;
        float* C = (float*)(ws + OFF_GP) + ((i64)(b * 2 + sp) * 50 + r) * 8192;
        gemm64(A, SQ, B, SQ, r / 5, r % 5, 1024, 3, C, 0, nullptr, nullptr, pool);
    } else {
        const int j = x * 90 + (o - 50);         // 0..719
        if (j < 400) {            // U[h] -> Ucat col h*640 (bx 0..9)
            const int h = j / 50, r = j % 50;
            gemm64((const u16*)(ws + OFF_WQT) + (i64)h * EP * EB, EB,
                   (const u16*)(ws + OFF_WKT) + (i64)h * EP * EB, EB,
                   r / 5, r % 5, EB, 0,
                   (u16*)(ws + OFF_UCAT) + (i64)h * EP, HEP,
                   nullptr, nullptr, pool);
        } else {                  // Z[h] -> Zcat col h*640 (bx 0..7)
            const int j2 = j - 400, h = j2 / 40, r = j2 % 40;
            gemm64((const u16*)(ws + OFF_WOB) + (i64)h * EB, (i64)NH * EB,
                   (const u16*)(ws + OFF_WVT) + (i64)h * EP * EB, EB,
                   r / 5, r % 5, EB, 0,
                   (u16*)(ws + OFF_ZCAT) + (i64)h * EP, HEP,
                   nullptr, nullptr, pool);
        }
    }
}

// ===== L2 gred: reduce 2 G partials -> bf16 Gb (200 blocks)
__global__ __launch_bounds__(256)
void gred(char* __restrict__ ws)
{
    const int u = blockIdx.x;
    const int b = u / 50, t = u % 50;
    const int bx = t / 5, by = t % 5;
    const int tid = threadIdx.x, lane = tid & 63, wid = tid >> 6;
    const int g = lane >> 4, li = lane & 15;
    const float* base = (const float*)(ws + OFF_GP) + ((i64)b * 2 * 50 + t) * 8192;
    u16* gb = (u16*)(ws + OFF_GB) + (i64)b * EP * EP;
#pragma unroll
    for (int fm = 0; fm < 4; ++fm)
#pragma unroll
        for (int fn = 0; fn < 2; ++fn) {
            const int fo = (fm * 2 + fn) * 1024 + tid * 4;
            f32x4 s = *(const f32x4*)(base + fo);
            f32x4 p1 = *(const f32x4*)(base + 50 * 8192 + fo);
            s[0] += p1[0]; s[1] += p1[1]; s[2] += p1[2]; s[3] += p1[3];
            const int row0 = bx * 64 + fm * 16 + g * 4;
            const int col = by * 128 + wid * 32 + fn * 16 + li;
#pragma unroll
            for (int qq = 0; qq < 4; ++qq)
                gb[(i64)(row0 + qq) * EP + col] = f2bf(s[qq]);
        }
}

// ===== L3 zg: ZG[b,h] = Z[h] * G[b]^T (1280 blocks, K=640)
__global__ __launch_bounds__(256)
void zg(char* __restrict__ ws)
{
    GEMM_LDS
    const int x = blockIdx.x & 7, o = blockIdx.x >> 3;
    const int id = x * 160 + o;
    const int z = id / 40, t = id % 40, b = z >> 3, h = z & 7;
    gemm64((const u16*)(ws + OFF_ZCAT) + (i64)h * EP, HEP,
           (const u16*)(ws + OFF_GB) + (i64)b * EP * EP, EP,
           t / 5, t % 5, EP, 0,
           (u16*)(ws + OFF_ZGC) + (i64)b * EB * HEP + (i64)h * EP, HEP,
           nullptr, nullptr, pool);
}

// ===== L4 ct: CT partials = ZGcat * Ucat^T (640 blocks, K=1280 splitK4)
__global__ __launch_bounds__(256)
void ct(char* __restrict__ ws)
{
    GEMM_LDS
    const int x = blockIdx.x & 7, o = blockIdx.x >> 3;
    const int id = x * 80 + o;
    const int z = id / 40, t = id % 40, b = z >> 2, sp = z & 3;
    const u16* A = (const u16*)(ws + OFF_ZGC) + (i64)b * EB * HEP + (i64)sp * 1280;
    const u16* B = (const u16*)(ws + OFF_UCAT) + (i64)sp * 1280;
    float* C = (float*)(ws + OFF_CTP) + ((i64)(b * 4 + sp) * 40 + t) * 8192;
    gemm64(A, HEP, B, HEP, t / 5, t % 5, 1280, 3, C, 0,
           nullptr, nullptr, pool);
}

// ===== L5 cvt2: CT reduce (160 blocks)
__global__ __launch_bounds__(256)
void cvt2(char* __restrict__ ws)
{
    const int u = blockIdx.x, tid = threadIdx.x;
    const int b = u / 40, t = u % 40;
    const int bx = t / 5, by = t % 5;
    const int lane = tid & 63, wid = tid >> 6;
    const int g = lane >> 4, li = lane & 15;
    const float* base = (const float*)(ws + OFF_CTP) + ((i64)b * 4 * 40 + t) * 8192;
    u16* ctb = (u16*)(ws + OFF_CTB) + (i64)b * EB * EP;
    float* rb = (float*)(ws + OFF_RB) + (i64)b * EB;
#pragma unroll
    for (int fm = 0; fm < 4; ++fm)
#pragma unroll
        for (int fn = 0; fn < 2; ++fn) {
            const int fo = (fm * 2 + fn) * 1024 + tid * 4;
            f32x4 s = *(const f32x4*)(base + fo);
#pragma unroll
            for (int p = 1; p < 4; ++p) {
                f32x4 pp = *(const f32x4*)(base + (i64)p * 40 * 8192 + fo);
                s[0] += pp[0]; s[1] += pp[1]; s[2] += pp[2]; s[3] += pp[3];
            }
            const int row0 = bx * 64 + fm * 16 + g * 4;
            const int col = by * 128 + wid * 32 + fn * 16 + li;
#pragma unroll
            for (int qq = 0; qq < 4; ++qq) {
                const float val = s[qq] * (1.0f / 512.0f);
                ctb[(i64)(row0 + qq) * EP + col] = f2bf(val);
                if (col == 512) rb[row0 + qq] = val;
            }
        }
}

// ===== L6 out: out[b] = q~[b] * CTb[b]^T + rb + bo (512 blocks, K=512)
__global__ __launch_bounds__(256)
void gout(char* __restrict__ ws, float* __restrict__ out,
          const float* __restrict__ bo)
{
    GEMM_LDS
    const int x = blockIdx.x & 7, o = blockIdx.x >> 3;
    const int id = x * 64 + o;
    const int b = id / 128, t = id % 128;
    gemm64((const u16*)(ws + OFF_QB) + (i64)b * SQ * EB, EB,
           (const u16*)(ws + OFF_CTB) + (i64)b * EB * EP, EP,
           t / 4, t % 4, EB, 2,
           out + (i64)b * SQ * EB, EB,
           (const float*)(ws + OFF_RB) + (i64)b * EB, bo, pool);
}

extern "C" void kernel_launch(void* const* d_in, const int* in_sizes, int n_in,
                              void* d_out, int out_size, void* d_ws, size_t ws_size,
                              hipStream_t stream)
{
    const float* q  = (const float*)d_in[0];
    const float* k  = (const float*)d_in[1];
    const float* v  = (const float*)d_in[2];
    const float* Wq = (const float*)d_in[3];
    const float* bq = (const float*)d_in[4];
    const float* Wk = (const float*)d_in[5];
    const float* bk = (const float*)d_in[6];
    const float* Wv = (const float*)d_in[7];
    const float* bv = (const float*)d_in[8];
    const float* Wo = (const float*)d_in[9];
    const float* bo = (const float*)d_in[10];
    float* out = (float*)d_out;
    char* ws = (char*)d_ws;
    (void)in_sizes; (void)n_in; (void)out_size; (void)ws_size;

    const dim3 blk(256);

    prep<<<dim3(6016), blk, 0, stream>>>(q, k, v, Wq, bq, Wk, bk, Wv, bv, Wo, ws);
    stage1<<<dim3(1120), blk, 0, stream>>>(ws);
    gred<<<dim3(200), blk, 0, stream>>>(ws);
    zg<<<dim3(1280), blk, 0, stream>>>(ws);
    ct<<<dim3(640), blk, 0, stream>>>(ws);
    cvt2<<<dim3(160), blk, 0, stream>>>(ws);
    gout<<<dim3(512), blk, 0, stream>>>(ws, out, bo);
}